// Round 1
// baseline (84.734 us; speedup 1.0000x reference)
//
#include <hip/hip_runtime.h>

// Problem constants (from reference init_kwargs)
constexpr int I_SAMPLES = 32768;
constexpr int K_WIDTH   = 32;
constexpr int NNODES    = 193;     // N_ELEM*N_ORDER + 1
constexpr int IK        = I_SAMPLES * K_WIDTH;

// One thread per (sample i, width k); k = tid & 31 -> fully coalesced output
// stores at c*IK + i*K + k == c*IK + tid.
__global__ __launch_bounds__(256) void kann_kernel(
    const float* __restrict__ x,      // (I, 4)
    const float* __restrict__ W_in,   // (32, 193, 4)
    const float* __restrict__ W_out,  // (32, 193)
    float* __restrict__ out)          // (4, I, 32) flat
{
    const int tid = blockIdx.x * blockDim.x + threadIdx.x;
    const int k = tid & 31;
    const int i = tid >> 5;

    // 32 lanes per sample read the same float4 -> broadcast from L1.
    const float4 xv = reinterpret_cast<const float4*>(x)[i];
    const float xj[4] = {xv.x, xv.y, xv.z, xv.w};

    // Cubic Lagrange basis on nodes {-1,-1/3,1/3,1} in monomial form.
    // phi_p(x) = C3*x^3 + C2*x^2 + C1*x + C0  (all coeffs exact in binary)
    const float C3[4] = {-0.5625f,  1.6875f, -1.6875f,  0.5625f};
    const float C2[4] = { 0.5625f, -0.5625f, -0.5625f,  0.5625f};
    const float C1[4] = { 0.0625f, -1.6875f,  1.6875f, -0.0625f};
    const float C0[4] = {-0.0625f,  0.5625f,  0.5625f, -0.0625f};

    float t = 0.f, dta = 0.f, dda = 0.f;
    const float* Wk = W_in + k * (NNODES * 4);

    #pragma unroll
    for (int j = 0; j < 4; ++j) {
        // layer_transform, inner domain [-1,1]: mirror reference fp32 op order
        const float xs = (192.0f * (xj[j] + 1.0f)) / 2.0f;
        float ide = floorf(xs / 3.0f);
        ide = fminf(fmaxf(ide, 0.0f), 63.0f);
        const int nl = (int)(ide * 3.0f);
        const float xr = (2.0f * (xs - (float)nl)) / 3.0f - 1.0f;

        #pragma unroll
        for (int p = 0; p < 4; ++p) {
            const float w     = Wk[(nl + p) * 4 + j];
            const float phi   = ((C3[p] * xr + C2[p]) * xr + C1[p]) * xr + C0[p];
            const float dphi  = (3.0f * C3[p] * xr + 2.0f * C2[p]) * xr + C1[p];
            const float ddphi = 6.0f * C3[p] * xr + 2.0f * C2[p];
            t   += w * phi;
            dta += w * dphi;
            dda += w * ddphi;
        }
    }
    // delta_in = 0.015625 (exact power of 2): /delta == *64, /delta^2 == *4096
    const float dt  = dta * 64.0f;
    const float ddt = dda * 4096.0f;

    // outer layer on t, domain [-3,3]
    const float xs2 = (192.0f * (t + 3.0f)) / 6.0f;
    float id2 = floorf(xs2 / 3.0f);
    id2 = fminf(fmaxf(id2, 0.0f), 63.0f);
    const int nl2 = (int)(id2 * 3.0f);
    const float xr2 = (2.0f * (xs2 - (float)nl2)) / 3.0f - 1.0f;

    float y = 0.f;
    const float* Wo = W_out + k * NNODES + nl2;
    #pragma unroll
    for (int p = 0; p < 4; ++p) {
        const float phi = ((C3[p] * xr2 + C2[p]) * xr2 + C1[p]) * xr2 + C0[p];
        y += Wo[p] * phi;
    }

    // out = stack([y, t, dt, ddt]) -> (4, I, K)
    out[tid]          = y;
    out[IK + tid]     = t;
    out[2 * IK + tid] = dt;
    out[3 * IK + tid] = ddt;
}

extern "C" void kernel_launch(void* const* d_in, const int* in_sizes, int n_in,
                              void* d_out, int out_size, void* d_ws, size_t ws_size,
                              hipStream_t stream) {
    const float* x     = (const float*)d_in[0];
    const float* W_in  = (const float*)d_in[1];
    const float* W_out = (const float*)d_in[2];
    float* out = (float*)d_out;

    dim3 grid(IK / 256), block(256);
    kann_kernel<<<grid, block, 0, stream>>>(x, W_in, W_out, out);
}

// Round 2
// 72.078 us; speedup vs baseline: 1.1756x; 1.1756x over previous
//
#include <hip/hip_runtime.h>

// Problem constants
constexpr int I_SAMPLES = 32768;
constexpr int K_WIDTH   = 32;
constexpr int NNODES    = 193;     // 64*3 + 1
constexpr int N_ELEM    = 64;
constexpr int IK        = I_SAMPLES * K_WIDTH;

// d_ws layout:
//   W1: float4[4][64][32]   -> W1[((j*64+e)*32)+k] = {W_in[k][3e+p][j]}p=0..3   (128 KB)
//   W2: float4[64][32]      -> W2[e*32+k]          = {W_out[k][3e+p]}p=0..3     ( 32 KB)
constexpr int W1_N = 4 * N_ELEM * K_WIDTH;   // 8192 float4
constexpr int W2_N = N_ELEM * K_WIDTH;       // 2048 float4

__global__ __launch_bounds__(256) void prep_kernel(
    const float* __restrict__ W_in,   // (32, 193, 4)
    const float* __restrict__ W_out,  // (32, 193)
    float4* __restrict__ W1,
    float4* __restrict__ W2)
{
    const int t = blockIdx.x * blockDim.x + threadIdx.x;
    if (t < W1_N) {
        const int k = t & 31;
        const int e = (t >> 5) & 63;
        const int j = t >> 11;                 // 0..3
        const int base = (k * NNODES + 3 * e) * 4 + j;
        float4 v;
        v.x = W_in[base + 0 * 4];
        v.y = W_in[base + 1 * 4];
        v.z = W_in[base + 2 * 4];
        v.w = W_in[base + 3 * 4];
        W1[t] = v;
    } else if (t < W1_N + W2_N) {
        const int u = t - W1_N;
        const int k = u & 31;
        const int e = u >> 5;
        const int base = k * NNODES + 3 * e;
        float4 v;
        v.x = W_out[base + 0];
        v.y = W_out[base + 1];
        v.z = W_out[base + 2];
        v.w = W_out[base + 3];
        W2[u] = v;
    }
}

// One thread per (i,k); k = tid & 31 -> coalesced stores AND coalesced
// W1/W2 gathers (k is the fastest-varying index of the repacked layout).
__global__ __launch_bounds__(256) void kann_kernel(
    const float* __restrict__ x,      // (I, 4)
    const float4* __restrict__ W1,
    const float4* __restrict__ W2,
    float* __restrict__ out)          // (4, I, 32) flat
{
    const int tid = blockIdx.x * blockDim.x + threadIdx.x;
    const int k = tid & 31;
    const int i = tid >> 5;

    const float4 xv = reinterpret_cast<const float4*>(x)[i];
    const float xj[4] = {xv.x, xv.y, xv.z, xv.w};

    // Cubic Lagrange basis on nodes {-1,-1/3,1/3,1}, monomial (exact) coeffs.
    const float C3[4] = {-0.5625f,  1.6875f, -1.6875f,  0.5625f};
    const float C2[4] = { 0.5625f, -0.5625f, -0.5625f,  0.5625f};
    const float C1[4] = { 0.0625f, -1.6875f,  1.6875f, -0.0625f};
    const float C0[4] = {-0.0625f,  0.5625f,  0.5625f, -0.0625f};

    float t = 0.f, dta = 0.f, dda = 0.f;

    #pragma unroll
    for (int j = 0; j < 4; ++j) {
        // inner transform, domain [-1,1] (mirror reference fp32 op order)
        const float xs = (192.0f * (xj[j] + 1.0f)) / 2.0f;
        float ide = floorf(xs / 3.0f);
        ide = fminf(fmaxf(ide, 0.0f), 63.0f);
        const int e  = (int)ide;
        const int nl = 3 * e;
        const float xr = (2.0f * (xs - (float)nl)) / 3.0f - 1.0f;

        const float4 w = W1[(j * N_ELEM + e) * K_WIDTH + k];
        const float wv[4] = {w.x, w.y, w.z, w.w};

        #pragma unroll
        for (int p = 0; p < 4; ++p) {
            const float phi   = ((C3[p] * xr + C2[p]) * xr + C1[p]) * xr + C0[p];
            const float dphi  = (3.0f * C3[p] * xr + 2.0f * C2[p]) * xr + C1[p];
            const float ddphi = 6.0f * C3[p] * xr + 2.0f * C2[p];
            t   += wv[p] * phi;
            dta += wv[p] * dphi;
            dda += wv[p] * ddphi;
        }
    }
    // delta_in = 1/64 exactly
    const float dt  = dta * 64.0f;
    const float ddt = dda * 4096.0f;

    // outer transform, domain [-3,3]
    const float xs2 = (192.0f * (t + 3.0f)) / 6.0f;
    float id2 = floorf(xs2 / 3.0f);
    id2 = fminf(fmaxf(id2, 0.0f), 63.0f);
    const int e2  = (int)id2;
    const int nl2 = 3 * e2;
    const float xr2 = (2.0f * (xs2 - (float)nl2)) / 3.0f - 1.0f;

    const float4 w2 = W2[e2 * K_WIDTH + k];
    const float w2v[4] = {w2.x, w2.y, w2.z, w2.w};
    float y = 0.f;
    #pragma unroll
    for (int p = 0; p < 4; ++p) {
        const float phi = ((C3[p] * xr2 + C2[p]) * xr2 + C1[p]) * xr2 + C0[p];
        y += w2v[p] * phi;
    }

    out[tid]          = y;
    out[IK + tid]     = t;
    out[2 * IK + tid] = dt;
    out[3 * IK + tid] = ddt;
}

extern "C" void kernel_launch(void* const* d_in, const int* in_sizes, int n_in,
                              void* d_out, int out_size, void* d_ws, size_t ws_size,
                              hipStream_t stream) {
    const float* x     = (const float*)d_in[0];
    const float* W_in  = (const float*)d_in[1];
    const float* W_out = (const float*)d_in[2];
    float* out = (float*)d_out;

    float4* W1 = (float4*)d_ws;
    float4* W2 = W1 + W1_N;

    prep_kernel<<<(W1_N + W2_N + 255) / 256, 256, 0, stream>>>(W_in, W_out, W1, W2);
    kann_kernel<<<IK / 256, 256, 0, stream>>>(x, W1, W2, out);
}